// Round 3
// baseline (124.959 us; speedup 1.0000x reference)
//
#include <hip/hip_runtime.h>
#include <hip/hip_bf16.h>

#define IMG 256
#define SPLIT 4  // row-block waves per face

// One wave handles (face = wave % BF, sub = wave / BF): sub-major interleave
// puts 4 DIFFERENT faces in each 256-thread block (variance /4) and spreads a
// big face's subs across distant blocks. Projection is done in-wave: lanes
// 0..2 each project one vertex (numpy-exact fp32 op order), then broadcast.
__global__ __launch_bounds__(256) void raster_kernel(
        const float* __restrict__ verts, const int* __restrict__ faces,
        const float* __restrict__ cams, float* __restrict__ out,
        int B, int V, int F) {
    int gid  = blockIdx.x * blockDim.x + threadIdx.x;
    int wave = gid >> 6;
    int lane = gid & 63;
    int BF = B * F;
    if (wave >= BF * SPLIT) return;
    int sub  = wave / BF;
    int widx = wave - sub * BF;
    int b    = widx / F;

    const int* fp = faces + (size_t)widx * 3;
    int i0 = fp[0], i1 = fp[1], i2 = fp[2];
    int vidx = (lane == 1) ? i1 : (lane == 2) ? i2 : i0;

    // --- in-wave projection (lanes 0..2 meaningful), numpy fp32 op order ---
    const float* vb = verts + (size_t)b * V * 3;
    float f  = __fadd_rn(__fmul_rn(1.0f, cams[b * 3 + 0]), 0.0f);
    float cx = cams[b * 3 + 1];
    float cy = cams[b * 3 + 2];
    float image_size = __fmul_rn(cams[1], 2.0f);  // cam[0,1] * 2.0
    float X = vb[vidx * 3 + 0];
    float Y = vb[vidx * 3 + 1];
    float Z = __fadd_rn(vb[vidx * 3 + 2], 0.0f);
    float ppx = __fadd_rn(__fdiv_rn(__fmul_rn(f, X), Z), cx);
    float ppy = __fadd_rn(__fdiv_rn(__fmul_rn(f, Y), Z), cy);
    float nx = __fsub_rn(__fmul_rn(__fdiv_rn(ppx, image_size), 2.0f), 1.0f);
    float ny = __fsub_rn(__fmul_rn(__fdiv_rn(ppy, image_size), 2.0f), 1.0f);
    float2 v0 = make_float2(__shfl(nx, 0, 64), __shfl(ny, 0, 64));
    float2 v1 = make_float2(__shfl(nx, 1, 64), __shfl(ny, 1, 64));
    float2 v2 = make_float2(__shfl(nx, 2, 64), __shfl(ny, 2, 64));

    // area, exact np fp32 order
    float area = __fsub_rn(
        __fmul_rn(__fsub_rn(v1.x, v0.x), __fsub_rn(v2.y, v0.y)),
        __fmul_rn(__fsub_rn(v1.y, v0.y), __fsub_rn(v2.x, v0.x)));
    if (!(fabsf(area) > 1e-12f)) return;

    // Conservative bbox: center(i) = (2i+1)/256-1 => i = 128*v + 127.5
    float xmn = fminf(v0.x, fminf(v1.x, v2.x));
    float xmx = fmaxf(v0.x, fmaxf(v1.x, v2.x));
    float ymn = fminf(v0.y, fminf(v1.y, v2.y));
    float ymx = fmaxf(v0.y, fmaxf(v1.y, v2.y));
    int ix0 = max(0,       (int)floorf(xmn * 128.0f + 127.5f) - 1);
    int ix1 = min(IMG - 1, (int)ceilf (xmx * 128.0f + 127.5f) + 1);
    int iy0 = max(0,       (int)floorf(ymn * 128.0f + 127.5f) - 1);
    int iy1 = min(IMG - 1, (int)ceilf (ymx * 128.0f + 127.5f) + 1);
    if (ix1 < ix0 || iy1 < iy0) return;
    int W = ix1 - ix0 + 1, H = iy1 - iy0 + 1;

    // Lane tile shape (TW x TH, TW*TH = 64) minimizing wave-iterations.
    int tws = 6, bestIt = ((W + 63) >> 6) * H;
    int it;
    it = ((W + 31) >> 5) * ((H + 1) >> 1); if (it < bestIt) { bestIt = it; tws = 5; }
    it = ((W + 15) >> 4) * ((H + 3) >> 2); if (it < bestIt) { bestIt = it; tws = 4; }
    it = ((W + 7)  >> 3) * ((H + 7) >> 3); if (it < bestIt) { bestIt = it; tws = 3; }
    int TW = 1 << tws, TH = 64 >> tws;
    int dx = lane & (TW - 1), dy = lane >> tws;

    // Loop-invariant edge deltas (individually rounded, matching np)
    float e0x = __fsub_rn(v2.x, v1.x), e0y = __fsub_rn(v2.y, v1.y);
    float e1x = __fsub_rn(v0.x, v2.x), e1y = __fsub_rn(v0.y, v2.y);
    float e2x = __fsub_rn(v1.x, v0.x), e2y = __fsub_rn(v1.y, v0.y);

    float* outb = out + (size_t)b * IMG * IMG;
    float pxStep = (float)TW * 0.0078125f;  // TW*2/256, exact power of two

    for (int ty = iy0 + sub * TH; ty <= iy1; ty += SPLIT * TH) {
        int y = ty + dy;
        bool yok = (y <= iy1);
        float py = (float)(2 * y + 1) * 0.00390625f - 1.0f;  // exact
        float t0 = __fmul_rn(__fsub_rn(py, v1.y), e0x);
        float t1 = __fmul_rn(__fsub_rn(py, v2.y), e1x);
        float t2 = __fmul_rn(__fsub_rn(py, v0.y), e2x);
        float* p = outb + y * IMG + ix0 + dx;
        int x = ix0 + dx;
        float px = (float)(2 * x + 1) * 0.00390625f - 1.0f;  // exact
        for (int tx = ix0; tx <= ix1; tx += TW) {
            float w0 = __fsub_rn(__fmul_rn(__fsub_rn(px, v1.x), e0y), t0);
            float w1 = __fsub_rn(__fmul_rn(__fsub_rn(px, v2.x), e1y), t1);
            float w2 = __fsub_rn(__fmul_rn(__fsub_rn(px, v0.x), e2y), t2);
            float mn = fminf(w0, fminf(w1, w2));   // v_min3
            float mx = fmaxf(w0, fmaxf(w1, w2));   // v_max3
            bool inside = (mn >= 0.f) | (mx <= 0.f);
            if (inside & yok & (x <= ix1)) *p = 1.0f;
            px += pxStep;  // exact, bit-identical to direct eval
            x  += TW;
            p  += TW;
        }
    }
}

extern "C" void kernel_launch(void* const* d_in, const int* in_sizes, int n_in,
                              void* d_out, int out_size, void* d_ws, size_t ws_size,
                              hipStream_t stream) {
    const float* verts = (const float*)d_in[0];
    const int*   faces = (const int*)d_in[1];
    const float* cams  = (const float*)d_in[2];
    float* out = (float*)d_out;

    int B = in_sizes[2] / 3;
    int V = in_sizes[0] / (3 * B);
    int F = in_sizes[1] / (3 * B);

    // Zero the fp32 output image via a lightweight memset node.
    hipMemsetAsync(d_out, 0, (size_t)out_size * sizeof(float), stream);

    long long nthreads = (long long)B * F * SPLIT * 64;
    hipLaunchKernelGGL(raster_kernel, dim3((nthreads + 255) / 256), dim3(256), 0,
                       stream, verts, faces, cams, out, B, V, F);
}